// Round 11
// baseline (132.011 us; speedup 1.0000x reference)
//
#include <hip/hip_runtime.h>

#define Bsz 64
#define Nn  256
#define Ee  20   // atom embedding dim
#define Dd  25   // gaussian centers
#define NBLK 2048  // 2048 blocks x 4 waves x 2 rows = 16384 (b,i) rows

using short8  = __attribute__((ext_vector_type(8))) short;  // 8 bf16 (4 VGPRs)
using floatx4 = __attribute__((ext_vector_type(4))) float;  // 4 fp32 acc
using f32x2   = __attribute__((ext_vector_type(2))) float;  // v_pk_* pair
using u32x2   = __attribute__((ext_vector_type(2))) unsigned;

#if __has_builtin(__builtin_amdgcn_exp2f)
#define EXP2F(x) __builtin_amdgcn_exp2f(x)
#else
#define EXP2F(x) __expf(0.6931471805599453f * (x))
#endif
#if __has_builtin(__builtin_amdgcn_rcpf)
#define RCPF(x) __builtin_amdgcn_rcpf(x)
#else
#define RCPF(x) (1.0f / (x))
#endif
#if __has_builtin(__builtin_elementwise_fma)
#define PKFMA(a, b, c) __builtin_elementwise_fma((a), (b), (c))
#else
#define PKFMA(a, b, c) ((a) * (b) + (c))   // hip contracts to fma by default
#endif

__device__ __forceinline__ short f2bf(float x) {            // RNE fp32->bf16
    unsigned u = __float_as_uint(x);
    unsigned r = (u + 0x7FFFu + ((u >> 16) & 1u)) >> 16;
    return (short)r;
}
__device__ __forceinline__ float bf2f(short h) {
    return __uint_as_float(((unsigned)(unsigned short)h) << 16);
}
__device__ __forceinline__ float tanhfast(float x) {
    float e = __expf(2.0f * x);
    return 1.0f - 2.0f / (e + 1.0f);
}
// combine two pre-biased uints (val+0x8000) into packed bf16 pair
__device__ __forceinline__ unsigned permpack(unsigned aBits, unsigned bBits) {
#if __has_builtin(__builtin_amdgcn_perm)
    return __builtin_amdgcn_perm(bBits, aBits, 0x07060302u);
#else
    return (aBits >> 16) | (bBits & 0xFFFF0000u);
#endif
}

// ---- workspace layout (bytes from d_ws base; all 16B-aligned) ----
#define WS_FRAGHI 0       // short[2*64*8]  = 2048 B
#define WS_FRAGLO 2048    // short[2*64*8]  = 2048 B
#define WS_ABK    4096    // float[256*20]  = 20480 B
#define WS_CF     24576   // float[256*20]  = 20480 B
#define WS_U      45056   // float[20]      = 80 B
#define WS_PART   45184   // float[2048]    = 8192 B
// total 53376 B

// One-block setup: lane-native weight fragments (cj power-tree constants
// folded), per-z bias/cfeat tables, folded top-MLP vector u.
__global__ __launch_bounds__(256) void dtnn_setup(
    const float* __restrict__ Vw, const float* __restrict__ Vb,
    const float* __restrict__ emb,
    const float* __restrict__ W1, const float* __restrict__ W2,
    short* __restrict__ fragHi, short* __restrict__ fragLo,
    float* __restrict__ AbK, float* __restrict__ cfT, float* __restrict__ uT)
{
    const int tid = threadIdx.x;
    const float Kc = 2.8853900817779268f;   // 2*log2(e)
    // cj[jj] = e^{-0.08 jj^2}: folds the Gaussian cross-terms so in-loop
    // g_{k0+jj} = g0 * t^jj with t = e^{0.8u} (shallow power tree)
    const float cj[8] = {1.0f, 0.9231163463866358f, 0.7261490370736909f,
                         0.48675225595997157f, 0.2780373004531941f,
                         0.1353352832366127f, 0.05613476283303940f,
                         0.019841459768337877f};

    if (tid < 64) {
        const int c16 = tid & 15, k0 = (tid >> 4) * 8;
        #pragma unroll
        for (int nt = 0; nt < 2; ++nt) {
            #pragma unroll
            for (int jj = 0; jj < 8; ++jj) {
                const int o = nt * 16 + c16, k = k0 + jj;
                float wvf = (o < Ee && k < Dd)
                          ? Kc * cj[jj] * Vw[o * 45 + 20 + k] : 0.0f;
                short h = f2bf(wvf);
                fragHi[(nt * 64 + tid) * 8 + jj] = h;
                fragLo[(nt * 64 + tid) * 8 + jj] = f2bf(wvf - bf2f(h));
            }
        }
    }
    if (tid < Ee) {
        float uo = 0.0f;
        #pragma unroll
        for (int p = 0; p < 10; ++p) uo = fmaf(W2[p], W1[p * Ee + tid], uo);
        uT[tid] = uo;
    }
    // per-z tables (depend only on the z VALUE)
    const int v = tid;
    const float m = (v != 0) ? 1.0f : 0.0f;
    for (int o = 0; o < Ee; ++o) {
        float dot = 0.0f;
        #pragma unroll
        for (int f = 0; f < Ee; ++f)
            dot = fmaf(Vw[o * 45 + f], emb[v * Ee + f], dot);
        AbK[v * Ee + o] = Kc * (Vb[o] + m * dot);
        cfT[v * Ee + o] = m * emb[v * Ee + o];
    }
}

// launch_bounds(256, 8): 8 waves/SIMD -> all 2048 blocks co-resident
// (256 CU x 8 blocks). VGPR=60 fits the 64-reg/wave budget at 8 waves.
// R10 ran (256,4): only half the grid resident -> 2 rounds, 30% occupancy.
__global__ __launch_bounds__(256, 8) void dtnn_main(
    const int*   __restrict__ z,      // [B,N]
    const float* __restrict__ dist,   // [B,N,N]
    const short* __restrict__ fragHi, // [2][64][8] lane-native
    const short* __restrict__ fragLo,
    const float* __restrict__ AbK,    // [256][20] by z-value
    const float* __restrict__ cfT,    // [256][20]
    const float* __restrict__ uT,     // [20]
    float*       __restrict__ part)   // [NBLK]
{
    const int tid  = threadIdx.x;
    const int lane = tid & 63;
    const int wave = tid >> 6;
    const int blk  = blockIdx.x;
    const int b    = blk >> 5;                        // 32 blocks per batch
    const int i0   = ((blk & 31) << 3) | (wave << 1); // rows i0, i0+1

    const int c16  = lane & 15;
    const int quad = lane >> 4;
    const int k0   = quad * 8;
    const float Kc  = 2.8853900817779268f;   // 2*log2(e)
    const float T04 = 1.1541560327111707f;   // 0.4*Kc (0.8u in exp2 domain)

    // dist rows up-front (8 coalesced b32 loads)
    const float* dr = dist + ((size_t)b * Nn + i0) * Nn;
    const float a0 = dr[lane],        a1 = dr[lane + 64];
    const float a2 = dr[lane + 128],  a3 = dr[lane + 192];
    const float e0 = dr[Nn + lane],       e1r = dr[Nn + lane + 64];
    const float e2 = dr[Nn + lane + 128], e3 = dr[Nn + lane + 192];

    // weight fragments: coalesced b128 table loads (cheap prologue - R8 evid.)
    const short8* fH = (const short8*)fragHi;
    const short8* fL = (const short8*)fragLo;
    short8 whiK[2], wloK[2];
    whiK[0] = fH[lane];  whiK[1] = fH[64 + lane];
    wloK[0] = fL[lane];  wloK[1] = fL[64 + lane];

    const int zi0 = z[b * Nn + i0];          // wave-uniform
    const int zi1 = z[b * Nn + i0 + 1];
    const float m0 = (zi0 != 0) ? 1.0f : 0.0f;
    const float m1 = (zi1 != 0) ? 1.0f : 0.0f;

    floatx4 bias[2][2];  // [row][nt]
    float cf[2][2], uo[2];
    #pragma unroll
    for (int nt = 0; nt < 2; ++nt) {
        const int o = nt * 16 + c16;
        const bool valid = (o < Ee);
        const float A0 = valid ? AbK[zi0 * Ee + o] : 0.0f;
        const float A1 = valid ? AbK[zi1 * Ee + o] : 0.0f;
        bias[0][nt] = (floatx4){A0, A0, A0, A0};
        bias[1][nt] = (floatx4){A1, A1, A1, A1};
        cf[0][nt] = valid ? cfT[zi0 * Ee + o] : 0.0f;
        cf[1][nt] = valid ? cfT[zi1 * Ee + o] : 0.0f;
        uo[nt]    = valid ? uT[o] : 0.0f;
    }

    // ---- main loop: 16 j-tiles x 2 rows; sum tanh = 256 - 2*sum sigma
    // All per-element math packed across the two rows (v_pk_* f32).
    const float mu0 = 0.2f * (float)k0;
    f32x2 Rnt0 = {0.0f, 0.0f};   // {row0, row1} sigma-sums, ntile 0
    f32x2 Rnt1 = {0.0f, 0.0f};

    #pragma unroll
    for (int t = 0; t < 16; ++t) {
        const int sl = 16 * (t & 3) + c16;
        // static mux after full unroll (zero instructions)
        const float dva = (t & 8) ? ((t & 4) ? a3 : a2) : ((t & 4) ? a1 : a0);
        const float dvb = (t & 8) ? ((t & 4) ? e3 : e2) : ((t & 4) ? e1r : e0);
        f32x2 d2;
        d2.x = __shfl(dva, sl, 64);
        d2.y = __shfl(dvb, sl, 64);

        // RBF: g0 = 2^{-Kc u^2}, t = 2^{T04 u}; power tree, cj in weights
        const f32x2 uu = d2 - mu0;
        const f32x2 q1 = uu * (-Kc);
        const f32x2 q2 = q1 * uu;            // -Kc u^2
        const f32x2 q3 = uu * T04;
        f32x2 g0, tp;
        g0.x = EXP2F(q2.x);  g0.y = EXP2F(q2.y);
        tp.x = EXP2F(q3.x);  tp.y = EXP2F(q3.y);
        const f32x2 t2 = tp * tp, t3 = t2 * tp, t4 = t2 * t2;
        const f32x2 x1 = g0 * tp, x2 = g0 * t2, x3 = g0 * t3, x4 = g0 * t4;
        const f32x2 x5 = x1 * t4, x6 = x2 * t4, x7 = x3 * t4;

        // bf16 pack: packed +0x8000 bias, then per-row byte-perm
        const u32x2 P0 = __builtin_bit_cast(u32x2, g0) + 0x8000u;
        const u32x2 P1 = __builtin_bit_cast(u32x2, x1) + 0x8000u;
        const u32x2 P2 = __builtin_bit_cast(u32x2, x2) + 0x8000u;
        const u32x2 P3 = __builtin_bit_cast(u32x2, x3) + 0x8000u;
        const u32x2 P4 = __builtin_bit_cast(u32x2, x4) + 0x8000u;
        const u32x2 P5 = __builtin_bit_cast(u32x2, x5) + 0x8000u;
        const u32x2 P6 = __builtin_bit_cast(u32x2, x6) + 0x8000u;
        const u32x2 P7 = __builtin_bit_cast(u32x2, x7) + 0x8000u;
        union { short8 s; unsigned u4[4]; } GA, GB;
        GA.u4[0] = permpack(P0.x, P1.x);  GB.u4[0] = permpack(P0.y, P1.y);
        GA.u4[1] = permpack(P2.x, P3.x);  GB.u4[1] = permpack(P2.y, P3.y);
        GA.u4[2] = permpack(P4.x, P5.x);  GB.u4[2] = permpack(P4.y, P5.y);
        GA.u4[3] = permpack(P6.x, P7.x);  GB.u4[3] = permpack(P6.y, P7.y);

        // 8 MFMAs (2 rows x 2 ntiles x hi/lo), bias as C operand
        floatx4 p00 = __builtin_amdgcn_mfma_f32_16x16x32_bf16(GA.s, whiK[0], bias[0][0], 0, 0, 0);
        p00 = __builtin_amdgcn_mfma_f32_16x16x32_bf16(GA.s, wloK[0], p00, 0, 0, 0);
        floatx4 p01 = __builtin_amdgcn_mfma_f32_16x16x32_bf16(GA.s, whiK[1], bias[0][1], 0, 0, 0);
        p01 = __builtin_amdgcn_mfma_f32_16x16x32_bf16(GA.s, wloK[1], p01, 0, 0, 0);
        floatx4 p10 = __builtin_amdgcn_mfma_f32_16x16x32_bf16(GB.s, whiK[0], bias[1][0], 0, 0, 0);
        p10 = __builtin_amdgcn_mfma_f32_16x16x32_bf16(GB.s, wloK[0], p10, 0, 0, 0);
        floatx4 p11 = __builtin_amdgcn_mfma_f32_16x16x32_bf16(GB.s, whiK[1], bias[1][1], 0, 0, 0);
        p11 = __builtin_amdgcn_mfma_f32_16x16x32_bf16(GB.s, wloK[1], p11, 0, 0, 0);

        // sigma sums, packed across rows, 1 rcp per 4 sigmas per row
        {
            f32x2 A0 = {EXP2F(p00[0]), EXP2F(p10[0])};  A0 += 1.0f;
            f32x2 A1 = {EXP2F(p00[1]), EXP2F(p10[1])};  A1 += 1.0f;
            f32x2 A2 = {EXP2F(p00[2]), EXP2F(p10[2])};  A2 += 1.0f;
            f32x2 A3 = {EXP2F(p00[3]), EXP2F(p10[3])};  A3 += 1.0f;
            const f32x2 q01 = A0 * A1, q23 = A2 * A3;
            const f32x2 num = PKFMA(q01, A2 + A3, q23 * (A0 + A1));
            const f32x2 den = q01 * q23;
            f32x2 rd;
            rd.x = RCPF(den.x);  rd.y = RCPF(den.y);
            Rnt0 = PKFMA(num, rd, Rnt0);
        }
        {
            f32x2 A0 = {EXP2F(p01[0]), EXP2F(p11[0])};  A0 += 1.0f;
            f32x2 A1 = {EXP2F(p01[1]), EXP2F(p11[1])};  A1 += 1.0f;
            f32x2 A2 = {EXP2F(p01[2]), EXP2F(p11[2])};  A2 += 1.0f;
            f32x2 A3 = {EXP2F(p01[3]), EXP2F(p11[3])};  A3 += 1.0f;
            const f32x2 q01 = A0 * A1, q23 = A2 * A3;
            const f32x2 num = PKFMA(q01, A2 + A3, q23 * (A0 + A1));
            const f32x2 den = q01 * q23;
            f32x2 rd;
            rd.x = RCPF(den.x);  rd.y = RCPF(den.y);
            Rnt1 = PKFMA(num, rd, Rnt1);
        }
    }

    // reduce sigma-sums over quads (per component)
    float R00 = Rnt0.x, R10 = Rnt0.y, R01 = Rnt1.x, R11 = Rnt1.y;
    R00 += __shfl_xor(R00, 16, 64);  R00 += __shfl_xor(R00, 32, 64);
    R01 += __shfl_xor(R01, 16, 64);  R01 += __shfl_xor(R01, 32, 64);
    R10 += __shfl_xor(R10, 16, 64);  R10 += __shfl_xor(R10, 32, 64);
    R11 += __shfl_xor(R11, 16, 64);  R11 += __shfl_xor(R11, 32, 64);

    // epilogue: th = tanh(cf + m*agg); e = sum_o u[o]*th[o], both rows
    float e = 0.0f;
    e = fmaf(tanhfast(cf[0][0] + m0 * (256.0f - 2.0f * R00)), uo[0], e);
    e = fmaf(tanhfast(cf[0][1] + m0 * (256.0f - 2.0f * R01)), uo[1], e);
    e = fmaf(tanhfast(cf[1][0] + m1 * (256.0f - 2.0f * R10)), uo[0], e);
    e = fmaf(tanhfast(cf[1][1] + m1 * (256.0f - 2.0f * R11)), uo[1], e);
    e += __shfl_xor(e, 1, 64);
    e += __shfl_xor(e, 2, 64);
    e += __shfl_xor(e, 4, 64);
    e += __shfl_xor(e, 8, 64);

    // block reduce: 4 waves -> one plain store (NO atomics)
    __shared__ float sE[4];
    if (lane == 0) sE[wave] = e;
    __syncthreads();
    if (tid == 0)
        part[blk] = sE[0] + sE[1] + sE[2] + sE[3];
}

// 64 blocks x 64 lanes: out[b] = sum of 32 block-partials + 256*C0
__global__ __launch_bounds__(64) void dtnn_reduce(
    const float* __restrict__ part,
    const float* __restrict__ b1, const float* __restrict__ W2,
    const float* __restrict__ b2, float* __restrict__ out)
{
    const int b = blockIdx.x;
    const int t = threadIdx.x;
    float v = (t < 32) ? part[b * 32 + t] : 0.0f;
    v += __shfl_xor(v, 1, 64);
    v += __shfl_xor(v, 2, 64);
    v += __shfl_xor(v, 4, 64);
    v += __shfl_xor(v, 8, 64);
    v += __shfl_xor(v, 16, 64);
    if (t == 0) {
        float c0 = b2[0];
        #pragma unroll
        for (int p = 0; p < 10; ++p) c0 = fmaf(W2[p], b1[p], c0);
        out[b] = v + 256.0f * c0;
    }
}

extern "C" void kernel_launch(void* const* d_in, const int* in_sizes, int n_in,
                              void* d_out, int out_size, void* d_ws, size_t ws_size,
                              hipStream_t stream) {
    const int*   z    = (const int*)  d_in[0];
    const float* dist = (const float*)d_in[1];
    const float* emb  = (const float*)d_in[2];
    const float* Vw   = (const float*)d_in[3];
    const float* Vb   = (const float*)d_in[4];
    const float* W1   = (const float*)d_in[5];
    const float* b1   = (const float*)d_in[6];
    const float* W2   = (const float*)d_in[7];
    const float* b2   = (const float*)d_in[8];
    float* out = (float*)d_out;

    char* ws = (char*)d_ws;
    short* fragHi = (short*)(ws + WS_FRAGHI);
    short* fragLo = (short*)(ws + WS_FRAGLO);
    float* AbK    = (float*)(ws + WS_ABK);
    float* cfT    = (float*)(ws + WS_CF);
    float* uT     = (float*)(ws + WS_U);
    float* partP  = (float*)(ws + WS_PART);

    dtnn_setup<<<1, 256, 0, stream>>>(Vw, Vb, emb, W1, W2,
                                      fragHi, fragLo, AbK, cfT, uT);

    // 2 rows/wave, table-based prologue, packed-f32 in-loop math,
    // full-grid residency (launch_bounds 256,8)
    dtnn_main<<<NBLK, 256, 0, stream>>>(
        z, dist, fragHi, fragLo, AbK, cfT, uT, partP);

    dtnn_reduce<<<Bsz, 64, 0, stream>>>(partP, b1, W2, b2, out);
}

// Round 12
// 121.899 us; speedup vs baseline: 1.0830x; 1.0830x over previous
//
#include <hip/hip_runtime.h>

#define Bsz 64
#define Nn  256
#define Ee  20   // atom embedding dim
#define Dd  25   // gaussian centers
#define NBLK 2048  // 2048 blocks x 4 waves x 2 rows = 16384 (b,i) rows

using short8  = __attribute__((ext_vector_type(8))) short;  // 8 bf16 (4 VGPRs)
using floatx4 = __attribute__((ext_vector_type(4))) float;  // 4 fp32 acc
using f32x2   = __attribute__((ext_vector_type(2))) float;  // v_pk_* pair
using u32x2   = __attribute__((ext_vector_type(2))) unsigned;

#if __has_builtin(__builtin_amdgcn_exp2f)
#define EXP2F(x) __builtin_amdgcn_exp2f(x)
#else
#define EXP2F(x) __expf(0.6931471805599453f * (x))
#endif
#if __has_builtin(__builtin_amdgcn_rcpf)
#define RCPF(x) __builtin_amdgcn_rcpf(x)
#else
#define RCPF(x) (1.0f / (x))
#endif
#if __has_builtin(__builtin_elementwise_fma)
#define PKFMA(a, b, c) __builtin_elementwise_fma((a), (b), (c))
#else
#define PKFMA(a, b, c) ((a) * (b) + (c))   // hip contracts to fma by default
#endif

__device__ __forceinline__ short f2bf(float x) {            // RNE fp32->bf16
    unsigned u = __float_as_uint(x);
    unsigned r = (u + 0x7FFFu + ((u >> 16) & 1u)) >> 16;
    return (short)r;
}
__device__ __forceinline__ float bf2f(short h) {
    return __uint_as_float(((unsigned)(unsigned short)h) << 16);
}
__device__ __forceinline__ float tanhfast(float x) {
    float e = __expf(2.0f * x);
    return 1.0f - 2.0f / (e + 1.0f);
}
// combine two pre-biased uints (val+0x8000) into packed bf16 pair
__device__ __forceinline__ unsigned permpack(unsigned aBits, unsigned bBits) {
#if __has_builtin(__builtin_amdgcn_perm)
    return __builtin_amdgcn_perm(bBits, aBits, 0x07060302u);
#else
    return (aBits >> 16) | (bBits & 0xFFFF0000u);
#endif
}

// ---- workspace layout (bytes from d_ws base; all 16B-aligned) ----
#define WS_FRAGHI 0       // short[2*64*8]  = 2048 B
#define WS_FRAGLO 2048    // short[2*64*8]  = 2048 B
#define WS_ABK    4096    // float[256*20]  = 20480 B
#define WS_CF     24576   // float[256*20]  = 20480 B
#define WS_U      45056   // float[20]      = 80 B
#define WS_PART   45184   // float[2048]    = 8192 B
// total 53376 B

// One-block setup: lane-native weight fragments (cj power-tree constants
// folded), per-z bias/cfeat tables, folded top-MLP vector u.
__global__ __launch_bounds__(256) void dtnn_setup(
    const float* __restrict__ Vw, const float* __restrict__ Vb,
    const float* __restrict__ emb,
    const float* __restrict__ W1, const float* __restrict__ W2,
    short* __restrict__ fragHi, short* __restrict__ fragLo,
    float* __restrict__ AbK, float* __restrict__ cfT, float* __restrict__ uT)
{
    const int tid = threadIdx.x;
    const float Kc = 2.8853900817779268f;   // 2*log2(e)
    // cj[jj] = e^{-0.08 jj^2}: folds the Gaussian cross-terms so in-loop
    // g_{k0+jj} = g0 * t^jj with t = e^{0.8u} (shallow power tree)
    const float cj[8] = {1.0f, 0.9231163463866358f, 0.7261490370736909f,
                         0.48675225595997157f, 0.2780373004531941f,
                         0.1353352832366127f, 0.05613476283303940f,
                         0.019841459768337877f};

    if (tid < 64) {
        const int c16 = tid & 15, k0 = (tid >> 4) * 8;
        #pragma unroll
        for (int nt = 0; nt < 2; ++nt) {
            #pragma unroll
            for (int jj = 0; jj < 8; ++jj) {
                const int o = nt * 16 + c16, k = k0 + jj;
                float wvf = (o < Ee && k < Dd)
                          ? Kc * cj[jj] * Vw[o * 45 + 20 + k] : 0.0f;
                short h = f2bf(wvf);
                fragHi[(nt * 64 + tid) * 8 + jj] = h;
                fragLo[(nt * 64 + tid) * 8 + jj] = f2bf(wvf - bf2f(h));
            }
        }
    }
    if (tid < Ee) {
        float uo = 0.0f;
        #pragma unroll
        for (int p = 0; p < 10; ++p) uo = fmaf(W2[p], W1[p * Ee + tid], uo);
        uT[tid] = uo;
    }
    // per-z tables (depend only on the z VALUE)
    const int v = tid;
    const float m = (v != 0) ? 1.0f : 0.0f;
    for (int o = 0; o < Ee; ++o) {
        float dot = 0.0f;
        #pragma unroll
        for (int f = 0; f < Ee; ++f)
            dot = fmaf(Vw[o * 45 + f], emb[v * Ee + f], dot);
        AbK[v * Ee + o] = Kc * (Vb[o] + m * dot);
        cfT[v * Ee + o] = m * emb[v * Ee + o];
    }
}

// launch_bounds(256, 6): 6 waves/SIMD (~84 VGPR cap) -- the occupancy bin
// that fits this kernel's ~60-68 reg need WITHOUT spilling. R11's (256,8)
// squeezed to 32 VGPR + scratch spills (WRITE_SIZE 64KB->33MB, FETCH +16MB)
// and regressed; R10's (256,4) left half the latency-hiding on the table.
__global__ __launch_bounds__(256, 6) void dtnn_main(
    const int*   __restrict__ z,      // [B,N]
    const float* __restrict__ dist,   // [B,N,N]
    const short* __restrict__ fragHi, // [2][64][8] lane-native
    const short* __restrict__ fragLo,
    const float* __restrict__ AbK,    // [256][20] by z-value
    const float* __restrict__ cfT,    // [256][20]
    const float* __restrict__ uT,     // [20]
    float*       __restrict__ part)   // [NBLK]
{
    const int tid  = threadIdx.x;
    const int lane = tid & 63;
    const int wave = tid >> 6;
    const int blk  = blockIdx.x;
    const int b    = blk >> 5;                        // 32 blocks per batch
    const int i0   = ((blk & 31) << 3) | (wave << 1); // rows i0, i0+1

    const int c16  = lane & 15;
    const int quad = lane >> 4;
    const int k0   = quad * 8;
    const float Kc  = 2.8853900817779268f;   // 2*log2(e)
    const float T04 = 1.1541560327111707f;   // 0.4*Kc (0.8u in exp2 domain)

    // dist rows up-front (8 coalesced b32 loads)
    const float* dr = dist + ((size_t)b * Nn + i0) * Nn;
    const float a0 = dr[lane],        a1 = dr[lane + 64];
    const float a2 = dr[lane + 128],  a3 = dr[lane + 192];
    const float e0 = dr[Nn + lane],       e1r = dr[Nn + lane + 64];
    const float e2 = dr[Nn + lane + 128], e3 = dr[Nn + lane + 192];

    // weight fragments: coalesced b128 table loads (cheap prologue - R8 evid.)
    const short8* fH = (const short8*)fragHi;
    const short8* fL = (const short8*)fragLo;
    short8 whiK[2], wloK[2];
    whiK[0] = fH[lane];  whiK[1] = fH[64 + lane];
    wloK[0] = fL[lane];  wloK[1] = fL[64 + lane];

    const int zi0 = z[b * Nn + i0];          // wave-uniform
    const int zi1 = z[b * Nn + i0 + 1];
    const float m0 = (zi0 != 0) ? 1.0f : 0.0f;
    const float m1 = (zi1 != 0) ? 1.0f : 0.0f;

    floatx4 bias[2][2];  // [row][nt]
    float cf[2][2], uo[2];
    #pragma unroll
    for (int nt = 0; nt < 2; ++nt) {
        const int o = nt * 16 + c16;
        const bool valid = (o < Ee);
        const float A0 = valid ? AbK[zi0 * Ee + o] : 0.0f;
        const float A1 = valid ? AbK[zi1 * Ee + o] : 0.0f;
        bias[0][nt] = (floatx4){A0, A0, A0, A0};
        bias[1][nt] = (floatx4){A1, A1, A1, A1};
        cf[0][nt] = valid ? cfT[zi0 * Ee + o] : 0.0f;
        cf[1][nt] = valid ? cfT[zi1 * Ee + o] : 0.0f;
        uo[nt]    = valid ? uT[o] : 0.0f;
    }

    // ---- main loop: 16 j-tiles x 2 rows; sum tanh = 256 - 2*sum sigma
    // All per-element math packed across the two rows (v_pk_* f32).
    const float mu0 = 0.2f * (float)k0;
    f32x2 Rnt0 = {0.0f, 0.0f};   // {row0, row1} sigma-sums, ntile 0
    f32x2 Rnt1 = {0.0f, 0.0f};

    #pragma unroll
    for (int t = 0; t < 16; ++t) {
        const int sl = 16 * (t & 3) + c16;
        // static mux after full unroll (zero instructions)
        const float dva = (t & 8) ? ((t & 4) ? a3 : a2) : ((t & 4) ? a1 : a0);
        const float dvb = (t & 8) ? ((t & 4) ? e3 : e2) : ((t & 4) ? e1r : e0);
        f32x2 d2;
        d2.x = __shfl(dva, sl, 64);
        d2.y = __shfl(dvb, sl, 64);

        // RBF: g0 = 2^{-Kc u^2}, t = 2^{T04 u}; power tree, cj in weights
        const f32x2 uu = d2 - mu0;
        const f32x2 q1 = uu * (-Kc);
        const f32x2 q2 = q1 * uu;            // -Kc u^2
        const f32x2 q3 = uu * T04;
        f32x2 g0, tp;
        g0.x = EXP2F(q2.x);  g0.y = EXP2F(q2.y);
        tp.x = EXP2F(q3.x);  tp.y = EXP2F(q3.y);
        const f32x2 t2 = tp * tp, t3 = t2 * tp, t4 = t2 * t2;
        const f32x2 x1 = g0 * tp, x2 = g0 * t2, x3 = g0 * t3, x4 = g0 * t4;
        const f32x2 x5 = x1 * t4, x6 = x2 * t4, x7 = x3 * t4;

        // bf16 pack: packed +0x8000 bias, then per-row byte-perm
        const u32x2 P0 = __builtin_bit_cast(u32x2, g0) + 0x8000u;
        const u32x2 P1 = __builtin_bit_cast(u32x2, x1) + 0x8000u;
        const u32x2 P2 = __builtin_bit_cast(u32x2, x2) + 0x8000u;
        const u32x2 P3 = __builtin_bit_cast(u32x2, x3) + 0x8000u;
        const u32x2 P4 = __builtin_bit_cast(u32x2, x4) + 0x8000u;
        const u32x2 P5 = __builtin_bit_cast(u32x2, x5) + 0x8000u;
        const u32x2 P6 = __builtin_bit_cast(u32x2, x6) + 0x8000u;
        const u32x2 P7 = __builtin_bit_cast(u32x2, x7) + 0x8000u;
        union { short8 s; unsigned u4[4]; } GA, GB;
        GA.u4[0] = permpack(P0.x, P1.x);  GB.u4[0] = permpack(P0.y, P1.y);
        GA.u4[1] = permpack(P2.x, P3.x);  GB.u4[1] = permpack(P2.y, P3.y);
        GA.u4[2] = permpack(P4.x, P5.x);  GB.u4[2] = permpack(P4.y, P5.y);
        GA.u4[3] = permpack(P6.x, P7.x);  GB.u4[3] = permpack(P6.y, P7.y);

        // 8 MFMAs (2 rows x 2 ntiles x hi/lo), bias as C operand
        floatx4 p00 = __builtin_amdgcn_mfma_f32_16x16x32_bf16(GA.s, whiK[0], bias[0][0], 0, 0, 0);
        p00 = __builtin_amdgcn_mfma_f32_16x16x32_bf16(GA.s, wloK[0], p00, 0, 0, 0);
        floatx4 p01 = __builtin_amdgcn_mfma_f32_16x16x32_bf16(GA.s, whiK[1], bias[0][1], 0, 0, 0);
        p01 = __builtin_amdgcn_mfma_f32_16x16x32_bf16(GA.s, wloK[1], p01, 0, 0, 0);
        floatx4 p10 = __builtin_amdgcn_mfma_f32_16x16x32_bf16(GB.s, whiK[0], bias[1][0], 0, 0, 0);
        p10 = __builtin_amdgcn_mfma_f32_16x16x32_bf16(GB.s, wloK[0], p10, 0, 0, 0);
        floatx4 p11 = __builtin_amdgcn_mfma_f32_16x16x32_bf16(GB.s, whiK[1], bias[1][1], 0, 0, 0);
        p11 = __builtin_amdgcn_mfma_f32_16x16x32_bf16(GB.s, wloK[1], p11, 0, 0, 0);

        // sigma sums, packed across rows, 1 rcp per 4 sigmas per row
        {
            f32x2 A0 = {EXP2F(p00[0]), EXP2F(p10[0])};  A0 += 1.0f;
            f32x2 A1 = {EXP2F(p00[1]), EXP2F(p10[1])};  A1 += 1.0f;
            f32x2 A2 = {EXP2F(p00[2]), EXP2F(p10[2])};  A2 += 1.0f;
            f32x2 A3 = {EXP2F(p00[3]), EXP2F(p10[3])};  A3 += 1.0f;
            const f32x2 q01 = A0 * A1, q23 = A2 * A3;
            const f32x2 num = PKFMA(q01, A2 + A3, q23 * (A0 + A1));
            const f32x2 den = q01 * q23;
            f32x2 rd;
            rd.x = RCPF(den.x);  rd.y = RCPF(den.y);
            Rnt0 = PKFMA(num, rd, Rnt0);
        }
        {
            f32x2 A0 = {EXP2F(p01[0]), EXP2F(p11[0])};  A0 += 1.0f;
            f32x2 A1 = {EXP2F(p01[1]), EXP2F(p11[1])};  A1 += 1.0f;
            f32x2 A2 = {EXP2F(p01[2]), EXP2F(p11[2])};  A2 += 1.0f;
            f32x2 A3 = {EXP2F(p01[3]), EXP2F(p11[3])};  A3 += 1.0f;
            const f32x2 q01 = A0 * A1, q23 = A2 * A3;
            const f32x2 num = PKFMA(q01, A2 + A3, q23 * (A0 + A1));
            const f32x2 den = q01 * q23;
            f32x2 rd;
            rd.x = RCPF(den.x);  rd.y = RCPF(den.y);
            Rnt1 = PKFMA(num, rd, Rnt1);
        }
    }

    // reduce sigma-sums over quads (per component)
    float R00 = Rnt0.x, R10 = Rnt0.y, R01 = Rnt1.x, R11 = Rnt1.y;
    R00 += __shfl_xor(R00, 16, 64);  R00 += __shfl_xor(R00, 32, 64);
    R01 += __shfl_xor(R01, 16, 64);  R01 += __shfl_xor(R01, 32, 64);
    R10 += __shfl_xor(R10, 16, 64);  R10 += __shfl_xor(R10, 32, 64);
    R11 += __shfl_xor(R11, 16, 64);  R11 += __shfl_xor(R11, 32, 64);

    // epilogue: th = tanh(cf + m*agg); e = sum_o u[o]*th[o], both rows
    float e = 0.0f;
    e = fmaf(tanhfast(cf[0][0] + m0 * (256.0f - 2.0f * R00)), uo[0], e);
    e = fmaf(tanhfast(cf[0][1] + m0 * (256.0f - 2.0f * R01)), uo[1], e);
    e = fmaf(tanhfast(cf[1][0] + m1 * (256.0f - 2.0f * R10)), uo[0], e);
    e = fmaf(tanhfast(cf[1][1] + m1 * (256.0f - 2.0f * R11)), uo[1], e);
    e += __shfl_xor(e, 1, 64);
    e += __shfl_xor(e, 2, 64);
    e += __shfl_xor(e, 4, 64);
    e += __shfl_xor(e, 8, 64);

    // block reduce: 4 waves -> one plain store (NO atomics)
    __shared__ float sE[4];
    if (lane == 0) sE[wave] = e;
    __syncthreads();
    if (tid == 0)
        part[blk] = sE[0] + sE[1] + sE[2] + sE[3];
}

// 64 blocks x 64 lanes: out[b] = sum of 32 block-partials + 256*C0
__global__ __launch_bounds__(64) void dtnn_reduce(
    const float* __restrict__ part,
    const float* __restrict__ b1, const float* __restrict__ W2,
    const float* __restrict__ b2, float* __restrict__ out)
{
    const int b = blockIdx.x;
    const int t = threadIdx.x;
    float v = (t < 32) ? part[b * 32 + t] : 0.0f;
    v += __shfl_xor(v, 1, 64);
    v += __shfl_xor(v, 2, 64);
    v += __shfl_xor(v, 4, 64);
    v += __shfl_xor(v, 8, 64);
    v += __shfl_xor(v, 16, 64);
    if (t == 0) {
        float c0 = b2[0];
        #pragma unroll
        for (int p = 0; p < 10; ++p) c0 = fmaf(W2[p], b1[p], c0);
        out[b] = v + 256.0f * c0;
    }
}

extern "C" void kernel_launch(void* const* d_in, const int* in_sizes, int n_in,
                              void* d_out, int out_size, void* d_ws, size_t ws_size,
                              hipStream_t stream) {
    const int*   z    = (const int*)  d_in[0];
    const float* dist = (const float*)d_in[1];
    const float* emb  = (const float*)d_in[2];
    const float* Vw   = (const float*)d_in[3];
    const float* Vb   = (const float*)d_in[4];
    const float* W1   = (const float*)d_in[5];
    const float* b1   = (const float*)d_in[6];
    const float* W2   = (const float*)d_in[7];
    const float* b2   = (const float*)d_in[8];
    float* out = (float*)d_out;

    char* ws = (char*)d_ws;
    short* fragHi = (short*)(ws + WS_FRAGHI);
    short* fragLo = (short*)(ws + WS_FRAGLO);
    float* AbK    = (float*)(ws + WS_ABK);
    float* cfT    = (float*)(ws + WS_CF);
    float* uT     = (float*)(ws + WS_U);
    float* partP  = (float*)(ws + WS_PART);

    dtnn_setup<<<1, 256, 0, stream>>>(Vw, Vb, emb, W1, W2,
                                      fragHi, fragLo, AbK, cfT, uT);

    // 2 rows/wave, table-based prologue, packed-f32 in-loop math,
    // 6 waves/SIMD residency (no spills)
    dtnn_main<<<NBLK, 256, 0, stream>>>(
        z, dist, fragHi, fragLo, AbK, cfT, uT, partP);

    dtnn_reduce<<<Bsz, 64, 0, stream>>>(partP, b1, W2, b2, out);
}